// Round 1
// baseline (273.878 us; speedup 1.0000x reference)
//
#include <hip/hip_runtime.h>
#include <math.h>

#define NC 64          // quaternion channels
#define NB 32          // batch
#define PLANE 4096     // H*W
#define NSTAT 14
#define QBN_EPS 1e-5f

// ws layout (floats): [0, 14*NC) = per-channel raw sums; [14*NC, 14*NC + 20*NC) = per-channel A(16)+bias(4)

// stat order: 0..3 sum(r,i,j,k); 4..7 sum(rr,ii,jj,kk); 8..13 sum(ri,rj,rk,ij,ik,jk)

__global__ __launch_bounds__(256) void qbn_stats(const float* __restrict__ x,
                                                 float* __restrict__ sums) {
    const int blk = blockIdx.x;
    const int c = blk & (NC - 1);
    const int b = blk >> 6;

    const float4* __restrict__ pr = (const float4*)(x + (size_t)(b * 4 * NC + c) * PLANE);
    const float4* __restrict__ pi = pr + (size_t)NC * PLANE / 4;
    const float4* __restrict__ pj = pr + (size_t)2 * NC * PLANE / 4;
    const float4* __restrict__ pk = pr + (size_t)3 * NC * PLANE / 4;

    float s[NSTAT];
#pragma unroll
    for (int t = 0; t < NSTAT; ++t) s[t] = 0.0f;

#pragma unroll
    for (int it = 0; it < 4; ++it) {
        const int idx = it * 256 + threadIdx.x;   // float4 index within plane (1024 per plane)
        float4 r4 = pr[idx];
        float4 i4 = pi[idx];
        float4 j4 = pj[idx];
        float4 k4 = pk[idx];
        float rv[4] = {r4.x, r4.y, r4.z, r4.w};
        float iv[4] = {i4.x, i4.y, i4.z, i4.w};
        float jv[4] = {j4.x, j4.y, j4.z, j4.w};
        float kv[4] = {k4.x, k4.y, k4.z, k4.w};
#pragma unroll
        for (int l = 0; l < 4; ++l) {
            const float r = rv[l], i = iv[l], j = jv[l], k = kv[l];
            s[0] += r;  s[1] += i;  s[2] += j;  s[3] += k;
            s[4] = fmaf(r, r, s[4]);
            s[5] = fmaf(i, i, s[5]);
            s[6] = fmaf(j, j, s[6]);
            s[7] = fmaf(k, k, s[7]);
            s[8]  = fmaf(r, i, s[8]);
            s[9]  = fmaf(r, j, s[9]);
            s[10] = fmaf(r, k, s[10]);
            s[11] = fmaf(i, j, s[11]);
            s[12] = fmaf(i, k, s[12]);
            s[13] = fmaf(j, k, s[13]);
        }
    }

    // wave (64-lane) shuffle reduce for each stat
#pragma unroll
    for (int t = 0; t < NSTAT; ++t) {
        float v = s[t];
#pragma unroll
        for (int off = 32; off >= 1; off >>= 1) v += __shfl_down(v, off);
        s[t] = v;
    }

    __shared__ float red[4][NSTAT];
    const int wave = threadIdx.x >> 6;
    const int lane = threadIdx.x & 63;
    if (lane == 0) {
#pragma unroll
        for (int t = 0; t < NSTAT; ++t) red[wave][t] = s[t];
    }
    __syncthreads();
    if (threadIdx.x < NSTAT) {
        const int t = threadIdx.x;
        float v = red[0][t] + red[1][t] + red[2][t] + red[3][t];
        atomicAdd(&sums[c * NSTAT + t], v);
    }
}

__global__ void qbn_solve(const float* __restrict__ sums,
                          const float* __restrict__ g_rr, const float* __restrict__ g_ii,
                          const float* __restrict__ g_jj, const float* __restrict__ g_kk,
                          const float* __restrict__ g_ri, const float* __restrict__ g_rj,
                          const float* __restrict__ g_rk, const float* __restrict__ g_ij,
                          const float* __restrict__ g_ik, const float* __restrict__ g_jk,
                          const float* __restrict__ beta,
                          float* __restrict__ params) {
    const int c = threadIdx.x;
    if (c >= NC) return;
    const float inv_n = 1.0f / (float)(NB * PLANE);
    const float* S = sums + c * NSTAT;

    const float mr = S[0] * inv_n, mi = S[1] * inv_n, mj = S[2] * inv_n, mk = S[3] * inv_n;
    const float var_r = S[4] * inv_n - mr * mr + QBN_EPS;
    const float var_i = S[5] * inv_n - mi * mi + QBN_EPS;
    const float var_j = S[6] * inv_n - mj * mj + QBN_EPS;
    const float var_k = S[7] * inv_n - mk * mk + QBN_EPS;
    const float cov_ri = S[8] * inv_n - mr * mi;
    const float cov_rj = S[9] * inv_n - mr * mj;
    const float cov_rk = S[10] * inv_n - mr * mk;
    const float cov_ij = S[11] * inv_n - mi * mj;
    const float cov_ik = S[12] * inv_n - mi * mk;
    const float cov_jk = S[13] * inv_n - mj * mk;

    // Cholesky-style chain (matches reference exactly)
    const float w_rr = sqrtf(var_r);
    const float w_ri = cov_ri / w_rr;
    const float w_ii = sqrtf(var_i - w_ri * w_ri);
    const float w_rj = cov_rj / w_rr;
    const float w_ij = (cov_ij - w_ri * w_rj) / w_ii;
    const float w_jj = sqrtf(var_j - (w_ij * w_ij + w_rj * w_rj));
    const float w_rk = cov_rk / w_rr;
    const float w_ik = (cov_ik - w_ri * w_rk) / w_ii;
    const float w_jk = (cov_jk - (w_ij * w_ik + w_rj * w_rk)) / w_jj;
    const float w_kk = sqrtf(var_k - (w_jk * w_jk + w_ik * w_ik + w_rk * w_rk));

    // W: rows = (r_n,i_n,j_n,k_n), cols = (cr,ci,cj,ck) -- upper triangular
    float W[4][4] = {
        {w_rr, w_ri, w_rj, w_rk},
        {0.0f, w_ii, w_ij, w_ik},
        {0.0f, 0.0f, w_jj, w_jk},
        {0.0f, 0.0f, 0.0f, w_kk},
    };
    const float grr = g_rr[c], gii = g_ii[c], gjj = g_jj[c], gkk = g_kk[c];
    const float gri = g_ri[c], grj = g_rj[c], grk = g_rk[c];
    const float gij = g_ij[c], gik = g_ik[c], gjk = g_jk[c];
    float G[4][4] = {
        {grr, gri, grj, grk},
        {gri, gii, gij, gik},
        {grj, gij, gjj, gjk},
        {grk, gik, gjk, gkk},
    };

    float A[4][4];
#pragma unroll
    for (int p = 0; p < 4; ++p)
#pragma unroll
        for (int q = 0; q < 4; ++q) {
            float acc = 0.0f;
#pragma unroll
            for (int t = 0; t < 4; ++t) acc = fmaf(G[p][t], W[t][q], acc);
            A[p][q] = acc;
        }

    const float m[4] = {mr, mi, mj, mk};
    const float bb[4] = {beta[c], beta[NC + c], beta[2 * NC + c], beta[3 * NC + c]};

    float* P = params + c * 20;
#pragma unroll
    for (int p = 0; p < 4; ++p) {
#pragma unroll
        for (int q = 0; q < 4; ++q) P[p * 4 + q] = A[p][q];
        float bias = bb[p];
#pragma unroll
        for (int q = 0; q < 4; ++q) bias -= A[p][q] * m[q];
        P[16 + p] = bias;
    }
}

__global__ __launch_bounds__(256) void qbn_apply(const float* __restrict__ x,
                                                 const float* __restrict__ params,
                                                 float* __restrict__ out) {
    const int blk = blockIdx.x;
    const int c = blk & (NC - 1);
    const int b = blk >> 6;

    const float* __restrict__ P = params + c * 20;
    const float A00 = P[0],  A01 = P[1],  A02 = P[2],  A03 = P[3];
    const float A10 = P[4],  A11 = P[5],  A12 = P[6],  A13 = P[7];
    const float A20 = P[8],  A21 = P[9],  A22 = P[10], A23 = P[11];
    const float A30 = P[12], A31 = P[13], A32 = P[14], A33 = P[15];
    const float b0 = P[16], b1 = P[17], b2 = P[18], b3 = P[19];

    const size_t base = (size_t)(b * 4 * NC + c) * PLANE;
    const size_t comp_stride4 = (size_t)NC * PLANE / 4;  // float4 stride between components
    const float4* __restrict__ pr = (const float4*)(x + base);
    const float4* __restrict__ pi = pr + comp_stride4;
    const float4* __restrict__ pj = pr + 2 * comp_stride4;
    const float4* __restrict__ pk = pr + 3 * comp_stride4;
    float4* __restrict__ qr = (float4*)(out + base);
    float4* __restrict__ qi = qr + comp_stride4;
    float4* __restrict__ qj = qr + 2 * comp_stride4;
    float4* __restrict__ qk = qr + 3 * comp_stride4;

#pragma unroll
    for (int it = 0; it < 4; ++it) {
        const int idx = it * 256 + threadIdx.x;
        float4 r4 = pr[idx];
        float4 i4 = pi[idx];
        float4 j4 = pj[idx];
        float4 k4 = pk[idx];

        float rv[4] = {r4.x, r4.y, r4.z, r4.w};
        float iv[4] = {i4.x, i4.y, i4.z, i4.w};
        float jv[4] = {j4.x, j4.y, j4.z, j4.w};
        float kv[4] = {k4.x, k4.y, k4.z, k4.w};
        float o0[4], o1[4], o2[4], o3[4];
#pragma unroll
        for (int l = 0; l < 4; ++l) {
            const float r = rv[l], i = iv[l], j = jv[l], k = kv[l];
            o0[l] = fmaf(A00, r, fmaf(A01, i, fmaf(A02, j, fmaf(A03, k, b0))));
            o1[l] = fmaf(A10, r, fmaf(A11, i, fmaf(A12, j, fmaf(A13, k, b1))));
            o2[l] = fmaf(A20, r, fmaf(A21, i, fmaf(A22, j, fmaf(A23, k, b2))));
            o3[l] = fmaf(A30, r, fmaf(A31, i, fmaf(A32, j, fmaf(A33, k, b3))));
        }
        qr[idx] = make_float4(o0[0], o0[1], o0[2], o0[3]);
        qi[idx] = make_float4(o1[0], o1[1], o1[2], o1[3]);
        qj[idx] = make_float4(o2[0], o2[1], o2[2], o2[3]);
        qk[idx] = make_float4(o3[0], o3[1], o3[2], o3[3]);
    }
}

extern "C" void kernel_launch(void* const* d_in, const int* in_sizes, int n_in,
                              void* d_out, int out_size, void* d_ws, size_t ws_size,
                              hipStream_t stream) {
    const float* x     = (const float*)d_in[0];
    const float* g_rr  = (const float*)d_in[1];
    const float* g_ii  = (const float*)d_in[2];
    const float* g_jj  = (const float*)d_in[3];
    const float* g_kk  = (const float*)d_in[4];
    const float* g_ri  = (const float*)d_in[5];
    const float* g_rj  = (const float*)d_in[6];
    const float* g_rk  = (const float*)d_in[7];
    const float* g_ij  = (const float*)d_in[8];
    const float* g_ik  = (const float*)d_in[9];
    const float* g_jk  = (const float*)d_in[10];
    const float* beta  = (const float*)d_in[11];
    float* out = (float*)d_out;

    float* sums   = (float*)d_ws;          // 14*64 floats
    float* params = sums + NSTAT * NC;     // 20*64 floats

    hipMemsetAsync(d_ws, 0, NSTAT * NC * sizeof(float), stream);

    qbn_stats<<<NB * NC, 256, 0, stream>>>(x, sums);
    qbn_solve<<<1, 64, 0, stream>>>(sums, g_rr, g_ii, g_jj, g_kk,
                                    g_ri, g_rj, g_rk, g_ij, g_ik, g_jk, beta, params);
    qbn_apply<<<NB * NC, 256, 0, stream>>>(x, params, out);
}